// Round 7
// baseline (461.193 us; speedup 1.0000x reference)
//
#include <hip/hip_runtime.h>

#define N_GRAPHS 100000
#define NTYPES 8
#define MAXD 128
#define FEAT 256
#define NBLK 1024          // 256 CUs x 4 blocks/CU, all resident from t=0
#define NRMAX 98           // max graphs per block (100000/1024 rounded up)
#define NS 7               // ceil(98/16) M-subtiles, uniform for all blocks

typedef __attribute__((ext_vector_type(8))) short short8;
typedef __attribute__((ext_vector_type(4))) float f32x4;
typedef __attribute__((ext_vector_type(4))) unsigned uint4v;

// type order alternates big/small LDS buffer; KS/DIM indexed by TYPE id
constexpr int ORDER[NTYPES] = {3, 2, 7, 4, 1, 5, 0, 6};
constexpr int KSN[NTYPES]   = {1, 1, 2, 4, 2, 1, 1, 4};
constexpr int DIMS[NTYPES]  = {16, 32, 64, 128, 64, 32, 16, 128};
constexpr int LDA0 = 132, LDA1 = 68;                 // shorts; odd dword strides
constexpr int BASE0 = 0, BASE1 = NRMAX * LDA0;       // 12936
constexpr int LDS_SHORTS = BASE1 + NRMAX * LDA1;     // 19600 shorts = 39.2 KB

__device__ __forceinline__ unsigned f2bf_u(float f) {
    unsigned u = __builtin_bit_cast(unsigned, f);
    return (u + 0x7fffu + ((u >> 16) & 1u)) >> 16;   // round-to-nearest-even
}
__device__ __forceinline__ unsigned cvt2(float lo, float hi) {
    return f2bf_u(lo) | (f2bf_u(hi) << 16);
}
__device__ __forceinline__ short8 cvt8(f32x4 a, f32x4 b) {
    uint4v u;
    u.x = cvt2(a.x, a.y); u.y = cvt2(a.z, a.w);
    u.z = cvt2(b.x, b.y); u.w = cvt2(b.z, b.w);
    return __builtin_bit_cast(short8, u);
}

// --- W -> bf16 fragment prepack (R4 layout). wp[((((t*4+wb)*4+nt)*4+ks)*4+cgrp)*16+c16]
__global__ __launch_bounds__(256)
void prepack_w(const float* __restrict__ W, short8* __restrict__ wp)
{
    const int idx  = blockIdx.x * 256 + threadIdx.x;   // 32768
    const int c16  = idx & 15;
    const int cgrp = (idx >> 4) & 3;
    const int ks   = (idx >> 6) & 3;
    const int nt   = (idx >> 8) & 3;
    const int wb   = (idx >> 10) & 3;
    const int t    = (idx >> 12) & 7;
    const int col  = wb * 64 + nt * 16 + c16;
    const int k    = ks * 32 + cgrp * 8;
    const int dim  = 16 << ((0x30123210u >> (4 * t)) & 0xf);
    const float* src = W + ((size_t)t * FEAT + col) * MAXD + k;
    f32x4 a = *(const f32x4*)src;
    f32x4 b = *(const f32x4*)(src + 4);
    #pragma unroll
    for (int j = 0; j < 4; ++j) {
        if (k + j     >= dim) a[j] = 0.f;
        if (k + 4 + j >= dim) b[j] = 0.f;
    }
    wp[idx] = cvt8(a, b);
}

// --- stage one type's A tile: nrows x K32, f32 -> bf16 -> LDS ---
template<int K32, int LDA_, int BASE_>
__device__ __forceinline__ void stage(const float* __restrict__ x, int gstart, int nrows,
                                      int t, unsigned short* __restrict__ lds, int tid)
{
    constexpr int TPR    = K32 / 8;            // threads per row
    constexpr int RPP    = 256 / TPR;          // rows per pass
    constexpr int PASSES = (NRMAX + RPP - 1) / RPP;
    const int rloc = tid / TPR;
    const int kg   = tid % TPR;
    #pragma unroll
    for (int p = 0; p < PASSES; ++p) {
        const int row = p * RPP + rloc;
        if (row < nrows) {
            const float* rp = x + ((size_t)(gstart + row) * NTYPES + t) * MAXD + kg * 8;
            f32x4 v0 = __builtin_nontemporal_load((const f32x4*)rp);
            f32x4 v1 = __builtin_nontemporal_load((const f32x4*)rp + 1);
            *(short8*)&lds[BASE_ + row * LDA_ + kg * 8] = cvt8(v0, v1);
        }
    }
}

template<int I, bool PRE>
__device__ __forceinline__ void type_step(const float* __restrict__ x,
                                          const short8* __restrict__ wp,
                                          const float* __restrict__ W,
                                          const float* __restrict__ bias_g,
                                          float* __restrict__ out,
                                          unsigned short* __restrict__ lds,
                                          int gstart, int nrows,
                                          int wave, int cgrp, int c16, int tid)
{
    constexpr int T     = ORDER[I];
    constexpr int KS    = KSN[T];
    constexpr int LDA_  = (I & 1) ? LDA1 : LDA0;
    constexpr int BASE_ = (I & 1) ? BASE1 : BASE0;

    // B fragments + bias (independent of LDS; issued before barrier)
    short8 Bf[KS][4];
    float  bias[4];
    #pragma unroll
    for (int nt = 0; nt < 4; ++nt) {
        bias[nt] = bias_g[T * FEAT + wave * 64 + nt * 16 + c16];
        if constexpr (PRE) {
            #pragma unroll
            for (int ks = 0; ks < KS; ++ks)
                Bf[ks][nt] = wp[((((T * 4 + wave) * 4 + nt) * 4 + ks) * 4 + cgrp) * 16 + c16];
        } else {
            constexpr int DIM = DIMS[T];
            const int col = wave * 64 + nt * 16 + c16;
            #pragma unroll
            for (int ks = 0; ks < KS; ++ks) {
                const int k = ks * 32 + cgrp * 8;
                const float* wf = W + ((size_t)T * FEAT + col) * MAXD + k;
                f32x4 a = *(const f32x4*)wf;
                f32x4 b = *(const f32x4*)(wf + 4);
                #pragma unroll
                for (int j = 0; j < 4; ++j) {
                    if (k + j     >= DIM) a[j] = 0.f;
                    if (k + 4 + j >= DIM) b[j] = 0.f;
                }
                Bf[ks][nt] = cvt8(a, b);
            }
        }
    }

    __syncthreads();   // stage(I) complete; compute(I-1) done -> buffer (I+1)&1 free

    if constexpr (I + 1 < NTYPES) {
        constexpr int TN    = ORDER[I + 1];
        constexpr int KN32  = KSN[TN] * 32;
        constexpr int LDAN  = ((I + 1) & 1) ? LDA1 : LDA0;
        constexpr int BASEN = ((I + 1) & 1) ? BASE1 : BASE0;
        stage<KN32, LDAN, BASEN>(x, gstart, nrows, TN, lds, tid);  // overlaps compute(I)
    }

    #pragma unroll
    for (int ms = 0; ms < NS; ++ms) {
        int arow = ms * 16 + c16;
        if (arow > nrows - 1) arow = nrows - 1;    // clamp: stay in-bounds, masked below
        short8 a[KS];
        #pragma unroll
        for (int ks = 0; ks < KS; ++ks)
            a[ks] = *(const short8*)&lds[BASE_ + arow * LDA_ + ks * 32 + cgrp * 8];

        f32x4 acc[4] = {{0,0,0,0},{0,0,0,0},{0,0,0,0},{0,0,0,0}};
        #pragma unroll
        for (int ks = 0; ks < KS; ++ks) {
            #pragma unroll
            for (int nt = 0; nt < 4; ++nt)
                acc[nt] = __builtin_amdgcn_mfma_f32_16x16x32_bf16(a[ks], Bf[ks][nt], acc[nt], 0, 0, 0);
        }

        const bool full = (ms * 16 + 16 <= nrows);
        #pragma unroll
        for (int nt = 0; nt < 4; ++nt) {
            const int col = wave * 64 + nt * 16 + c16;
            #pragma unroll
            for (int r = 0; r < 4; ++r) {
                const int lrow = ms * 16 + cgrp * 4 + r;   // C/D: row = cgrp*4 + reg
                if (full || lrow < nrows)
                    __builtin_nontemporal_store(acc[nt][r] + bias[nt],
                        &out[((size_t)(gstart + lrow) * NTYPES + T) * FEAT + col]);
            }
        }
    }

    if constexpr (I + 1 < NTYPES)
        type_step<I + 1, PRE>(x, wp, W, bias_g, out, lds, gstart, nrows, wave, cgrp, c16, tid);
}

// 1024 persistent blocks (4/CU, all resident, zero packing loss), each owns a
// contiguous 97-98 graph range. Types sequential per block (B fragments loaded
// once per type per block from L2-hot wp); asymmetric LDS double-buffer
// (98x132 + 98x68 shorts = 39.2 KB) keeps stage(t+1) overlapped with compute(t).
template<bool PRE>
__global__ __launch_bounds__(256, 4)
void node_enc(const float* __restrict__ x, const short8* __restrict__ wp,
              const float* __restrict__ W, const float* __restrict__ bias_g,
              float* __restrict__ out)
{
    __shared__ __align__(16) unsigned short lds[LDS_SHORTS];
    const int tid  = threadIdx.x;
    const int lane = tid & 63;
    const int wave = tid >> 6;
    const int cgrp = lane >> 4;
    const int c16  = lane & 15;
    const long long b = blockIdx.x;
    const int gstart = (int)(b * N_GRAPHS / NBLK);
    const int gend   = (int)((b + 1) * N_GRAPHS / NBLK);
    const int nrows  = gend - gstart;   // 97 or 98

    stage<KSN[ORDER[0]] * 32, LDA0, BASE0>(x, gstart, nrows, ORDER[0], lds, tid);
    type_step<0, PRE>(x, wp, W, bias_g, out, lds, gstart, nrows, wave, cgrp, c16, tid);
}

extern "C" void kernel_launch(void* const* d_in, const int* in_sizes, int n_in,
                              void* d_out, int out_size, void* d_ws, size_t ws_size,
                              hipStream_t stream)
{
    const float* x = (const float*)d_in[0];
    const float* W = (const float*)d_in[1];
    const float* b = (const float*)d_in[2];
    float* out = (float*)d_out;

    const size_t wp_bytes = (size_t)32768 * sizeof(short8);   // 512 KB

    if (ws_size >= wp_bytes) {
        short8* wp = (short8*)d_ws;
        prepack_w<<<128, 256, 0, stream>>>(W, wp);
        node_enc<true><<<NBLK, 256, 0, stream>>>(x, wp, W, b, out);
    } else {
        node_enc<false><<<NBLK, 256, 0, stream>>>(x, nullptr, W, b, out);
    }
}

// Round 8
// 416.260 us; speedup vs baseline: 1.1079x; 1.1079x over previous
//
#include <hip/hip_runtime.h>

#define N_GRAPHS 100000
#define NTYPES 8
#define MAXD 128
#define FEAT 256
#define NBATCH 2
#define GPW (16 * NBATCH)    // 32 graphs per wave
#define GPB (GPW * 4)        // 128 graphs per block (4 independent waves)

typedef __attribute__((ext_vector_type(8))) short short8;
typedef __attribute__((ext_vector_type(4))) float f32x4;
typedef __attribute__((ext_vector_type(4))) unsigned uint4v;

constexpr int KSN[NTYPES]  = {1, 1, 2, 4, 2, 1, 1, 4};
constexpr int DIMS[NTYPES] = {16, 32, 64, 128, 64, 32, 16, 128};

__device__ __forceinline__ unsigned f2bf_u(float f) {
    unsigned u = __builtin_bit_cast(unsigned, f);
    return (u + 0x7fffu + ((u >> 16) & 1u)) >> 16;   // round-to-nearest-even
}
__device__ __forceinline__ unsigned cvt2(float lo, float hi) {
    return f2bf_u(lo) | (f2bf_u(hi) << 16);
}
__device__ __forceinline__ short8 cvt8(f32x4 a, f32x4 b) {
    uint4v u;
    u.x = cvt2(a.x, a.y); u.y = cvt2(a.z, a.w);
    u.z = cvt2(b.x, b.y); u.w = cvt2(b.z, b.w);
    return __builtin_bit_cast(short8, u);
}

// --- W -> bf16 A-fragment prepack. wp[(((t*16 + ct)*4 + ks)*4 + cgrp)*16 + c16]
//     = W[t][ct*16 + c16][ks*32 + cgrp*8 .. +7], zero-masked at k >= dim. 512 KB.
__global__ __launch_bounds__(256)
void prepack_w(const float* __restrict__ W, short8* __restrict__ wp)
{
    const int idx  = blockIdx.x * 256 + threadIdx.x;   // 32768
    const int c16  = idx & 15;
    const int cgrp = (idx >> 4) & 3;
    const int ks   = (idx >> 6) & 3;
    const int ct   = (idx >> 8) & 15;
    const int t    = (idx >> 12) & 7;
    const int col  = ct * 16 + c16;
    const int k    = ks * 32 + cgrp * 8;
    const int dim  = 16 << ((0x30123210u >> (4 * t)) & 0xf);
    const float* src = W + ((size_t)t * FEAT + col) * MAXD + k;
    f32x4 a = *(const f32x4*)src;
    f32x4 b = *(const f32x4*)(src + 4);
    #pragma unroll
    for (int j = 0; j < 4; ++j) {
        if (k + j     >= dim) a[j] = 0.f;
        if (k + 4 + j >= dim) b[j] = 0.f;
    }
    wp[idx] = cvt8(a, b);
}

// Swapped-operand MFMA: A = W (row = feature = lane&15), B = x (col = graph =
// lane&15, k = (lane>>4)*8 + j). D[row=feat][col=graph] -> each lane holds 4
// CONSECUTIVE features of one graph = one plain dwordx4 store. No LDS, no
// barriers: every wave streams independently.
template<int T, bool PRE>
__device__ __forceinline__ void do_type(const float* __restrict__ x,
                                        const short8* __restrict__ wp,
                                        const float* __restrict__ W,
                                        const float* __restrict__ bias_g,
                                        float* __restrict__ out,
                                        int g0, int cgrp, int c16)
{
    constexpr int KS  = KSN[T];
    constexpr int DIM = DIMS[T];

    // x fragments for NBATCH groups of 16 graphs (B-operand), bf16 in regs
    short8 xf[NBATCH][KS];
    #pragma unroll
    for (int b = 0; b < NBATCH; ++b) {
        int g = g0 + b * 16 + c16;
        if (g > N_GRAPHS - 1) g = N_GRAPHS - 1;   // clamp; stores masked below
        #pragma unroll
        for (int ks = 0; ks < KS; ++ks) {
            const int k = ks * 32 + cgrp * 8;
            if (DIM >= 32 || cgrp < 2) {          // k < DIM for every loaded elem
                const float* rp = x + ((size_t)g * NTYPES + T) * MAXD + k;
                f32x4 v0 = __builtin_nontemporal_load((const f32x4*)rp);
                f32x4 v1 = __builtin_nontemporal_load((const f32x4*)rp + 1);
                xf[b][ks] = cvt8(v0, v1);
            } else {
                xf[b][ks] = short8{0, 0, 0, 0, 0, 0, 0, 0};
            }
        }
    }

    // 16 feature-tiles of 16; W fragment reused across NBATCH graph groups
    #pragma unroll 4
    for (int ct = 0; ct < 16; ++ct) {
        short8 wf[KS];
        if constexpr (PRE) {
            #pragma unroll
            for (int ks = 0; ks < KS; ++ks)
                wf[ks] = wp[(((T * 16 + ct) * 4 + ks) * 4 + cgrp) * 16 + c16];
        } else {
            #pragma unroll
            for (int ks = 0; ks < KS; ++ks) {
                const int k = ks * 32 + cgrp * 8;
                const float* wfp = W + ((size_t)T * FEAT + ct * 16 + c16) * MAXD + k;
                f32x4 a = *(const f32x4*)wfp;
                f32x4 b = *(const f32x4*)(wfp + 4);
                #pragma unroll
                for (int j = 0; j < 4; ++j) {
                    if (k + j     >= DIM) a[j] = 0.f;
                    if (k + 4 + j >= DIM) b[j] = 0.f;
                }
                wf[ks] = cvt8(a, b);
            }
        }

        const f32x4 bv = *(const f32x4*)&bias_g[T * FEAT + ct * 16 + cgrp * 4];

        #pragma unroll
        for (int b = 0; b < NBATCH; ++b) {
            f32x4 acc = {0.f, 0.f, 0.f, 0.f};
            #pragma unroll
            for (int ks = 0; ks < KS; ++ks)
                acc = __builtin_amdgcn_mfma_f32_16x16x32_bf16(wf[ks], xf[b][ks], acc, 0, 0, 0);
            const int g = g0 + b * 16 + c16;
            if (g < N_GRAPHS) {
                f32x4 res;
                #pragma unroll
                for (int r = 0; r < 4; ++r) res[r] = acc[r] + bv[r];
                // feats ct*16 + cgrp*4 + 0..3 of graph g: plain full-line-merging store
                *(f32x4*)&out[((size_t)g * NTYPES + T) * FEAT + ct * 16 + cgrp * 4] = res;
            }
        }
    }

    if constexpr (T + 1 < NTYPES)
        do_type<T + 1, PRE>(x, wp, W, bias_g, out, g0, cgrp, c16);
}

template<bool PRE>
__global__ __launch_bounds__(256)
void node_enc(const float* __restrict__ x, const short8* __restrict__ wp,
              const float* __restrict__ W, const float* __restrict__ bias_g,
              float* __restrict__ out)
{
    const int tid  = threadIdx.x;
    const int lane = tid & 63;
    const int wave = tid >> 6;
    const int cgrp = lane >> 4;
    const int c16  = lane & 15;
    const int g0   = blockIdx.x * GPB + wave * GPW;
    if (g0 >= N_GRAPHS) return;   // whole-wave exit; no barriers anywhere

    do_type<0, PRE>(x, wp, W, bias_g, out, g0, cgrp, c16);
}

extern "C" void kernel_launch(void* const* d_in, const int* in_sizes, int n_in,
                              void* d_out, int out_size, void* d_ws, size_t ws_size,
                              hipStream_t stream)
{
    const float* x = (const float*)d_in[0];
    const float* W = (const float*)d_in[1];
    const float* b = (const float*)d_in[2];
    float* out = (float*)d_out;

    const int grid = (N_GRAPHS + GPB - 1) / GPB;              // 782
    const size_t wp_bytes = (size_t)32768 * sizeof(short8);   // 512 KB

    if (ws_size >= wp_bytes) {
        short8* wp = (short8*)d_ws;
        prepack_w<<<128, 256, 0, stream>>>(W, wp);
        node_enc<true><<<grid, 256, 0, stream>>>(x, wp, W, b, out);
    } else {
        node_enc<false><<<grid, 256, 0, stream>>>(x, nullptr, W, b, out);
    }
}

// Round 9
// 332.160 us; speedup vs baseline: 1.3885x; 1.2532x over previous
//
#include <hip/hip_runtime.h>
#include <hip/hip_bf16.h>

#define N_GRAPHS 100000
#define NTYPES 8
#define MAXD 128
#define FEAT 256
#define ROWS 64

typedef __attribute__((ext_vector_type(8))) short short8;
typedef __attribute__((ext_vector_type(4))) float f32x4;
typedef __attribute__((ext_vector_type(4))) unsigned uint4v;

constexpr int DIMS[NTYPES] = {16, 32, 64, 128, 64, 32, 16, 128};

__device__ __forceinline__ unsigned f2bf_u(float f) {
    unsigned u = __builtin_bit_cast(unsigned, f);
    return (u + 0x7fffu + ((u >> 16) & 1u)) >> 16;   // round-to-nearest-even
}
__device__ __forceinline__ unsigned cvt2(float lo, float hi) {
    return f2bf_u(lo) | (f2bf_u(hi) << 16);
}
__device__ __forceinline__ short8 cvt8(f32x4 a, f32x4 b) {
    uint4v u;
    u.x = cvt2(a.x, a.y); u.y = cvt2(a.z, a.w);
    u.z = cvt2(b.x, b.y); u.w = cvt2(b.z, b.w);
    return __builtin_bit_cast(short8, u);
}

// --- W -> bf16 MFMA-fragment prepack (runs every launch; deterministic) ---
// Layout: wp[((((t*4 + wave)*4 + nt)*4 + ks)*4 + cgrp)*16 + c16] = short8 of
// W[t][wave*64 + nt*16 + c16][ks*32 + cgrp*8 .. +7], zero-masked at k >= dim.
__global__ __launch_bounds__(256)
void prepack_w(const float* __restrict__ W, short8* __restrict__ wp)
{
    const int idx  = blockIdx.x * 256 + threadIdx.x;   // 32768 total
    const int c16  = idx & 15;
    const int cgrp = (idx >> 4) & 3;
    const int ks   = (idx >> 6) & 3;
    const int nt   = (idx >> 8) & 3;
    const int wb   = (idx >> 10) & 3;
    const int t    = (idx >> 12) & 7;
    const int col  = wb * 64 + nt * 16 + c16;
    const int k    = ks * 32 + cgrp * 8;
    const int dim  = 16 << ((0x30123210u >> (4 * t)) & 0xf);  // {16,32,64,128,64,32,16,128}
    const float* src = W + ((size_t)t * FEAT + col) * MAXD + k;
    f32x4 a = *(const f32x4*)src;
    f32x4 b = *(const f32x4*)(src + 4);
    #pragma unroll
    for (int j = 0; j < 4; ++j) {
        if (k + j     >= dim) a[j] = 0.f;
        if (k + 4 + j >= dim) b[j] = 0.f;
    }
    wp[idx] = cvt8(a, b);
}

// --- stage one type's A tile: ROWS x K32, f32 -> bf16 -> LDS ---
template<int K32>
__device__ __forceinline__ void stage_tile(const float* __restrict__ x, int grow0, int t,
                                           unsigned short (* __restrict__ As)[136], int tid)
{
    constexpr int TPR    = K32 / 8;     // threads per row
    constexpr int RPP    = 256 / TPR;   // rows per pass
    constexpr int PASSES = ROWS / RPP;
    const int rloc = tid / TPR;
    const int kg   = tid % TPR;
    #pragma unroll
    for (int p = 0; p < PASSES; ++p) {
        const int i = p * RPP + rloc;
        int g = grow0 + i;
        if (g >= N_GRAPHS) g = N_GRAPHS - 1;   // clamp; tail stores are guarded
        const float* rp = x + ((size_t)g * NTYPES + t) * MAXD + kg * 8;
        f32x4 v0 = __builtin_nontemporal_load((const f32x4*)rp);
        f32x4 v1 = __builtin_nontemporal_load((const f32x4*)rp + 1);
        *(short8*)&As[i][kg * 8] = cvt8(v0, v1);
    }
}

template<int T, bool PRE>
__device__ __forceinline__ void type_step(const float* __restrict__ x,
                                          const float* __restrict__ W,
                                          const float* __restrict__ bias_g,
                                          float* __restrict__ out,
                                          const short8* __restrict__ wp,
                                          unsigned short (* __restrict__ As)[ROWS][136],
                                          int grow0, int tid, bool full)
{
    constexpr int DIM = DIMS[T];
    constexpr int KS  = (DIM + 31) / 32;
    const int lane = tid & 63, wave = tid >> 6;
    const int cgrp = lane >> 4, c16 = lane & 15;
    const int n0   = wave * 64;

    short8 Bf[KS][4];
    float  bias[4];
    #pragma unroll
    for (int nt = 0; nt < 4; ++nt) {
        bias[nt] = bias_g[T * FEAT + n0 + nt * 16 + c16];
        if constexpr (PRE) {
            #pragma unroll
            for (int ks = 0; ks < KS; ++ks)
                Bf[ks][nt] = wp[((((T * 4 + wave) * 4 + nt) * 4 + ks) * 4 + cgrp) * 16 + c16];
        } else {
            const int col = n0 + nt * 16 + c16;
            #pragma unroll
            for (int ks = 0; ks < KS; ++ks) {
                const int k = ks * 32 + cgrp * 8;
                const float* wpf = W + ((size_t)T * FEAT + col) * MAXD + k;
                f32x4 w0 = *(const f32x4*)wpf;
                f32x4 w1 = *(const f32x4*)(wpf + 4);
                #pragma unroll
                for (int j = 0; j < 4; ++j) {
                    if (k + j     >= DIM) w0[j] = 0.f;
                    if (k + 4 + j >= DIM) w1[j] = 0.f;
                }
                Bf[ks][nt] = cvt8(w0, w1);
            }
        }
    }

    __syncthreads();   // staging(T) complete; also orders WAR on buffer (T+1)&1

    if constexpr (T + 1 < NTYPES)
        stage_tile<((DIMS[T + 1] + 31) / 32) * 32>(x, grow0, T + 1, As[(T + 1) & 1], tid);

    const unsigned short (* __restrict__ A)[136] = As[T & 1];
    #pragma unroll
    for (int ms = 0; ms < ROWS / 16; ++ms) {
        short8 a[KS];
        #pragma unroll
        for (int ks = 0; ks < KS; ++ks)
            a[ks] = *(const short8*)&A[ms * 16 + c16][ks * 32 + cgrp * 8];

        f32x4 acc[4] = {{0,0,0,0},{0,0,0,0},{0,0,0,0},{0,0,0,0}};
        #pragma unroll
        for (int ks = 0; ks < KS; ++ks) {
            #pragma unroll
            for (int nt = 0; nt < 4; ++nt)
                acc[nt] = __builtin_amdgcn_mfma_f32_16x16x32_bf16(a[ks], Bf[ks][nt], acc[nt], 0, 0, 0);
        }

        if (full) {
            #pragma unroll
            for (int nt = 0; nt < 4; ++nt) {
                const int col = n0 + nt * 16 + c16;
                #pragma unroll
                for (int r = 0; r < 4; ++r) {
                    const int g = grow0 + ms * 16 + cgrp * 4 + r;
                    out[((size_t)g * NTYPES + T) * FEAT + col] = acc[nt][r] + bias[nt];
                }
            }
        } else {
            #pragma unroll
            for (int nt = 0; nt < 4; ++nt) {
                const int col = n0 + nt * 16 + c16;
                #pragma unroll
                for (int r = 0; r < 4; ++r) {
                    const int g = grow0 + ms * 16 + cgrp * 4 + r;
                    if (g < N_GRAPHS)
                        out[((size_t)g * NTYPES + T) * FEAT + col] = acc[nt][r] + bias[nt];
                }
            }
        }
    }

    if constexpr (T + 1 < NTYPES)
        type_step<T + 1, PRE>(x, W, bias_g, out, wp, As, grow0, tid, full);
}

// One block: 4 waves, 64 graphs, ALL 8 types -> writes a dense contiguous
// 512 KB output region. A tiles double-buffered in LDS, one barrier per type.
// Stores are PLAIN (write-back, line-merging); only loads are non-temporal.
template<bool PRE>
__global__ __launch_bounds__(256, 4)
void node_enc_fused(const float* __restrict__ x, const float* __restrict__ W,
                    const float* __restrict__ bias_g, float* __restrict__ out,
                    const short8* __restrict__ wp)
{
    __shared__ __align__(16) unsigned short As[2][ROWS][136];
    const int tid   = threadIdx.x;
    const int grow0 = blockIdx.x * ROWS;
    const bool full = (grow0 + ROWS <= N_GRAPHS);

    stage_tile<((DIMS[0] + 31) / 32) * 32>(x, grow0, 0, As[0], tid);
    type_step<0, PRE>(x, W, bias_g, out, wp, As, grow0, tid, full);
}

extern "C" void kernel_launch(void* const* d_in, const int* in_sizes, int n_in,
                              void* d_out, int out_size, void* d_ws, size_t ws_size,
                              hipStream_t stream)
{
    const float* x = (const float*)d_in[0];
    const float* W = (const float*)d_in[1];
    const float* b = (const float*)d_in[2];
    float* out = (float*)d_out;

    const int chunks = (N_GRAPHS + ROWS - 1) / ROWS;   // 1563
    const size_t wp_bytes = (size_t)NTYPES * 4 * 4 * 4 * 4 * 16 * sizeof(short8);  // 512 KB

    if (ws_size >= wp_bytes) {
        short8* wp = (short8*)d_ws;
        prepack_w<<<128, 256, 0, stream>>>(W, wp);
        node_enc_fused<true><<<chunks, 256, 0, stream>>>(x, W, b, out, wp);
    } else {
        node_enc_fused<false><<<chunks, 256, 0, stream>>>(x, W, b, out, nullptr);
    }
}

// Round 10
// 281.691 us; speedup vs baseline: 1.6372x; 1.1792x over previous
//
#include <hip/hip_runtime.h>

#define N_GRAPHS 100000
#define NTYPES 8
#define MAXD 128
#define FEAT 256
#define ALDA 136   // As row stride, shorts (272B: 16B-aligned, bank-staggered)
#define ELDA 68    // Ep row stride, floats (272B)

typedef __attribute__((ext_vector_type(8))) short short8;
typedef __attribute__((ext_vector_type(4))) float f32x4;
typedef __attribute__((ext_vector_type(4))) unsigned uint4v;

constexpr int KSN[NTYPES]  = {1, 1, 2, 4, 2, 1, 1, 4};
constexpr int DIMS[NTYPES] = {16, 32, 64, 128, 64, 32, 16, 128};

__device__ __forceinline__ unsigned f2bf_u(float f) {
    unsigned u = __builtin_bit_cast(unsigned, f);
    return (u + 0x7fffu + ((u >> 16) & 1u)) >> 16;   // round-to-nearest-even
}
__device__ __forceinline__ unsigned cvt2(float lo, float hi) {
    return f2bf_u(lo) | (f2bf_u(hi) << 16);
}
__device__ __forceinline__ short8 cvt8(f32x4 a, f32x4 b) {
    uint4v u;
    u.x = cvt2(a.x, a.y); u.y = cvt2(a.z, a.w);
    u.z = cvt2(b.x, b.y); u.w = cvt2(b.z, b.w);
    return __builtin_bit_cast(short8, u);
}

// --- W -> bf16 fragment prepack. wp[(((t*16 + ct)*4 + ks)*4 + cgrp)*16 + c16]
//     = W[t][ct*16 + c16][ks*32 + cgrp*8 .. +7], zero-masked at k >= dim. 512 KB.
__global__ __launch_bounds__(256)
void prepack_w(const float* __restrict__ W, short8* __restrict__ wp)
{
    const int idx  = blockIdx.x * 256 + threadIdx.x;   // 32768
    const int c16  = idx & 15;
    const int cgrp = (idx >> 4) & 3;
    const int ks   = (idx >> 6) & 3;
    const int ct   = (idx >> 8) & 15;
    const int t    = (idx >> 12) & 7;
    const int col  = ct * 16 + c16;
    const int k    = ks * 32 + cgrp * 8;
    const int dim  = 16 << ((0x30123210u >> (4 * t)) & 0xf);
    const float* src = W + ((size_t)t * FEAT + col) * MAXD + k;
    f32x4 a = *(const f32x4*)src;
    f32x4 b = *(const f32x4*)(src + 4);
    #pragma unroll
    for (int j = 0; j < 4; ++j) {
        if (k + j     >= dim) a[j] = 0.f;
        if (k + 4 + j >= dim) b[j] = 0.f;
    }
    wp[idx] = cvt8(a, b);
}

// One type for one wave's 16 graphs. NO barriers anywhere: As/Ep are
// wave-private LDS; ordering is intra-wave lgkmcnt (DS pipe is in-order).
template<int T, bool PRE>
__device__ __forceinline__ void do_type(const float* __restrict__ x,
                                        const short8* __restrict__ wp,
                                        const float* __restrict__ W,
                                        const float* __restrict__ bias_g,
                                        float* __restrict__ out,
                                        unsigned short* __restrict__ as_,
                                        float* __restrict__ ep,
                                        int g0, int lane, int cgrp, int c16)
{
    constexpr int KS   = KSN[T];
    constexpr int K32  = KS * 32;
    constexpr int SPR8 = K32 / 8;              // 8-float segments per row
    constexpr int PASSES = 16 * SPR8 / 64;     // lane-items / 64

    // --- stage x: 16 rows x K32 floats -> bf16 -> private As (coalesced nt) ---
    #pragma unroll
    for (int p = 0; p < PASSES; ++p) {
        const int idx = p * 64 + lane;
        const int row = idx / SPR8;
        const int s8  = idx % SPR8;
        const float* rp = x + (((size_t)(g0 + row)) * NTYPES + T) * MAXD + s8 * 8;
        f32x4 v0 = __builtin_nontemporal_load((const f32x4*)rp);
        f32x4 v1 = __builtin_nontemporal_load((const f32x4*)rp + 1);
        *(short8*)&as_[row * ALDA + s8 * 8] = cvt8(v0, v1);
    }

    // --- A fragments: row = graph = c16, k = ks*32 + cgrp*8 ---
    short8 a[KS];
    #pragma unroll
    for (int ks = 0; ks < KS; ++ks)
        a[ks] = *(const short8*)&as_[c16 * ALDA + ks * 32 + cgrp * 8];

    // --- 16 feature-tiles; flush Ep as dense 1KB stores every 4 tiles ---
    #pragma unroll
    for (int ct4 = 0; ct4 < 4; ++ct4) {
        #pragma unroll
        for (int c = 0; c < 4; ++c) {
            const int ct = ct4 * 4 + c;
            short8 wf[KS];
            if constexpr (PRE) {
                #pragma unroll
                for (int ks = 0; ks < KS; ++ks)
                    wf[ks] = wp[(((T * 16 + ct) * 4 + ks) * 4 + cgrp) * 16 + c16];
            } else {
                constexpr int DIM = DIMS[T];
                #pragma unroll
                for (int ks = 0; ks < KS; ++ks) {
                    const int k = ks * 32 + cgrp * 8;
                    const float* wfp = W + ((size_t)T * FEAT + ct * 16 + c16) * MAXD + k;
                    f32x4 wa = *(const f32x4*)wfp;
                    f32x4 wb = *(const f32x4*)(wfp + 4);
                    #pragma unroll
                    for (int j = 0; j < 4; ++j) {
                        if (k + j     >= DIM) wa[j] = 0.f;
                        if (k + 4 + j >= DIM) wb[j] = 0.f;
                    }
                    wf[ks] = cvt8(wa, wb);
                }
            }
            f32x4 acc = {0.f, 0.f, 0.f, 0.f};
            #pragma unroll
            for (int ks = 0; ks < KS; ++ks)
                acc = __builtin_amdgcn_mfma_f32_16x16x32_bf16(a[ks], wf[ks], acc, 0, 0, 0);
            // D: row (graph) = cgrp*4 + r, col (feat) = ct*16 + c16  [m89 layout]
            #pragma unroll
            for (int r = 0; r < 4; ++r)
                ep[(cgrp * 4 + r) * ELDA + (ct & 3) * 16 + c16] = acc[r];
        }
        // flush: 16 graphs x 64 feats -> 4 instrs x 1KB dense nt stores
        #pragma unroll
        for (int i = 0; i < 4; ++i) {
            const int row   = i * 4 + (lane >> 4);
            const int coldw = (lane & 15) * 4;
            f32x4 v  = *(const f32x4*)&ep[row * ELDA + coldw];        // ds_read_b128
            f32x4 b4 = *(const f32x4*)&bias_g[T * FEAT + ct4 * 64 + coldw];
            f32x4 res;
            #pragma unroll
            for (int r = 0; r < 4; ++r) res[r] = v[r] + b4[r];
            __builtin_nontemporal_store(res,
                (f32x4*)&out[(((size_t)(g0 + row)) * NTYPES + T) * FEAT + ct4 * 64 + coldw]);
        }
    }

    if constexpr (T + 1 < NTYPES)
        do_type<T + 1, PRE>(x, wp, W, bias_g, out, as_, ep, g0, lane, cgrp, c16);
}

// 4 fully independent waves per block, 16 graphs each (100000 = 6250*16 ->
// no partial tiles; surplus waves exit whole). Zero __syncthreads => no
// vmcnt(0) pipe drains; all LDS sync is intra-wave lgkmcnt.
template<bool PRE>
__global__ __launch_bounds__(256, 3)
void node_enc(const float* __restrict__ x, const short8* __restrict__ wp,
              const float* __restrict__ W, const float* __restrict__ bias_g,
              float* __restrict__ out)
{
    __shared__ __align__(16) unsigned short As[4][16 * ALDA];  // 17408 B
    __shared__ __align__(16) float          Ep[4][16 * ELDA];  // 17408 B
    const int tid  = threadIdx.x;
    const int lane = tid & 63;
    const int wave = tid >> 6;
    const int cgrp = lane >> 4;
    const int c16  = lane & 15;
    const int g0   = blockIdx.x * 64 + wave * 16;
    if (g0 >= N_GRAPHS) return;   // whole-wave exit (only in the last block)

    do_type<0, PRE>(x, wp, W, bias_g, out, As[wave], Ep[wave], g0, lane, cgrp, c16);
}

extern "C" void kernel_launch(void* const* d_in, const int* in_sizes, int n_in,
                              void* d_out, int out_size, void* d_ws, size_t ws_size,
                              hipStream_t stream)
{
    const float* x = (const float*)d_in[0];
    const float* W = (const float*)d_in[1];
    const float* b = (const float*)d_in[2];
    float* out = (float*)d_out;

    const int grid = (N_GRAPHS + 63) / 64;                    // 1563
    const size_t wp_bytes = (size_t)32768 * sizeof(short8);   // 512 KB

    if (ws_size >= wp_bytes) {
        short8* wp = (short8*)d_ws;
        prepack_w<<<128, 256, 0, stream>>>(W, wp);
        node_enc<true><<<grid, 256, 0, stream>>>(x, wp, W, b, out);
    } else {
        node_enc<false><<<grid, 256, 0, stream>>>(x, nullptr, W, b, out);
    }
}